// Round 1
// 732.385 us; speedup vs baseline: 1.1476x; 1.1476x over previous
//
#include <hip/hip_runtime.h>
#include <hip/hip_fp16.h>

// ---------------- problem constants ----------------
constexpr int   NN   = 100000;      // nodes
constexpr int   NE   = 3200000;     // edges
constexpr float BN_EPS = 1e-5f;

constexpr int MG_B  = (NN / 32 + 3) / 4;   // 782 mgemm blocks (3125 waves)
constexpr int NB    = (NN + 127) / 128;    // 782 buckets (128 nodes each)
constexpr int HB    = 256;                 // histogram / scatter blocks
constexpr int CHUNK = NE / HB;             // 12500 edges per chunk (exact)

typedef _Float16 half8 __attribute__((ext_vector_type(8)));
typedef float    floatx16 __attribute__((ext_vector_type(16)));

// ============================================================
// Weight prep (all 3): Wt[n][k] = fp16(W[k][n])
// ============================================================
__global__ __launch_bounds__(256) void k_wprep_all(const float* __restrict__ W1,
                                                   const float* __restrict__ W2,
                                                   const float* __restrict__ W3,
                                                   _Float16* __restrict__ Wt1,
                                                   _Float16* __restrict__ Wt2,
                                                   _Float16* __restrict__ Wt3) {
  int idx = blockIdx.x * 256 + threadIdx.x;
  if (idx < 16384) {
    int k = idx >> 7, n = idx & 127;
    Wt1[n * 128 + k] = (_Float16)W1[idx];
  } else if (idx < 32768) {
    int j = idx - 16384, k = j >> 7, n = j & 127;
    Wt2[n * 128 + k] = (_Float16)W2[j];
  } else if (idx < 40960) {
    int j = idx - 32768, k = j >> 6, n = j & 63;
    Wt3[n * 128 + k] = (_Float16)W3[j];
  }
}

// ============================================================
// F1: fused  [blocks 0..MG_B)       : layer-1 MFMA GEMM (UNSCALED fp16 out)
//            [MG_B..MG_B+HB)        : per-chunk LDS histogram over 782 buckets
// No global atomics anywhere: each hist block writes its own blkhist row.
// ============================================================
__global__ __launch_bounds__(256) void k_f1(const int* __restrict__ dst,
                                            int* __restrict__ blkhist,
                                            const float* __restrict__ x,
                                            const _Float16* __restrict__ Wt1,
                                            _Float16* __restrict__ C) {
  __shared__ int h[NB];
  if (blockIdx.x < MG_B) {
    // ---- mgemm<128, no BN, fp32 A, no dinv> ----
    int wid  = (blockIdx.x * 256 + threadIdx.x) >> 6;
    int lane = threadIdx.x & 63;
    if (wid >= NN / 32) return;
    const int m = lane & 31;
    const int q = lane >> 5;
    const int row0 = wid * 32;
    const float* Arow = x + (size_t)(row0 + m) * 128 + q * 8;

    floatx16 acc[4] = {};
#pragma unroll
    for (int s = 0; s < 8; ++s) {
      float4 a0 = *(const float4*)(Arow + 16 * s);
      float4 a1 = *(const float4*)(Arow + 16 * s + 4);
      half8 af;
      af[0] = (_Float16)a0.x; af[1] = (_Float16)a0.y;
      af[2] = (_Float16)a0.z; af[3] = (_Float16)a0.w;
      af[4] = (_Float16)a1.x; af[5] = (_Float16)a1.y;
      af[6] = (_Float16)a1.z; af[7] = (_Float16)a1.w;
#pragma unroll
      for (int ct = 0; ct < 4; ++ct) {
        half8 bf = *(const half8*)(Wt1 + (size_t)(ct * 32 + m) * 128 + q * 8 + 16 * s);
        acc[ct] = __builtin_amdgcn_mfma_f32_32x32x16_f16(af, bf, acc[ct], 0, 0, 0);
      }
    }
#pragma unroll
    for (int ct = 0; ct < 4; ++ct)
#pragma unroll
      for (int r = 0; r < 16; ++r) {
        int row = (r & 3) + 8 * (r >> 2) + 4 * q;   // C/D map [m74/m101]
        C[(size_t)(row0 + row) * 128 + ct * 32 + m] = (_Float16)acc[ct][r];
      }
  } else {
    int j = blockIdx.x - MG_B;        // chunk id 0..HB-1
    int t = threadIdx.x;
    for (int b = t; b < NB; b += 256) h[b] = 0;
    __syncthreads();
    int base = j * CHUNK;
    for (int e = base + t; e < base + CHUNK; e += 256)
      atomicAdd(&h[dst[e] >> 7], 1);                 // LDS atomic (fast)
    __syncthreads();
    for (int b = t; b < NB; b += 256) blkhist[j * NB + b] = h[b];
  }
}

// ============================================================
// Per-bucket exclusive scan over the 256 block counts.
// One wave per bucket; lane l handles blocks 4l..4l+3.
// ============================================================
__global__ __launch_bounds__(256) void k_scan_bkt_a(const int* __restrict__ blkhist,
                                                    int* __restrict__ blkbase,
                                                    int* __restrict__ total) {
  int wid  = (blockIdx.x * 256 + threadIdx.x) >> 6;
  int lane = threadIdx.x & 63;
  if (wid >= NB) return;
  int i0 = lane * 4;
  int v0 = blkhist[(i0 + 0) * NB + wid];
  int v1 = blkhist[(i0 + 1) * NB + wid];
  int v2 = blkhist[(i0 + 2) * NB + wid];
  int v3 = blkhist[(i0 + 3) * NB + wid];
  int lt = v0 + v1 + v2 + v3;
  int inc = lt;
#pragma unroll
  for (int off = 1; off < 64; off <<= 1) {
    int xx = __shfl_up(inc, off);
    if (lane >= off) inc += xx;
  }
  int exc = inc - lt;
  blkbase[(i0 + 0) * NB + wid] = exc;
  blkbase[(i0 + 1) * NB + wid] = exc + v0;
  blkbase[(i0 + 2) * NB + wid] = exc + v0 + v1;
  blkbase[(i0 + 3) * NB + wid] = exc + v0 + v1 + v2;
  if (lane == 63) total[wid] = inc;
}

// exclusive scan of 782 bucket totals -> bucket bases (+E sentinel)
__global__ __launch_bounds__(1024) void k_scan_bkt_b(const int* __restrict__ total,
                                                     int* __restrict__ bbase) {
  __shared__ int s[1024];
  int t = threadIdx.x;
  int v = (t < NB) ? total[t] : 0;
  s[t] = v;
  __syncthreads();
  for (int off = 1; off < 1024; off <<= 1) {
    int xx = (t >= off) ? s[t - off] : 0;
    __syncthreads();
    s[t] += xx;
    __syncthreads();
  }
  if (t < NB) bbase[t] = s[t] - v;
  if (t == NB - 1) bbase[NB] = s[t];   // == NE
}

// ============================================================
// Scatter edges into bucket order. Deterministic global positions:
// cursor[b] = bbase[b] + blkbase[chunk][b]; local order via LDS atomics.
// Packed edge: src (17b) | dlow (7b) << 17
// ============================================================
__global__ __launch_bounds__(256) void k_scatter(const int* __restrict__ ei,
                                                 const int* __restrict__ bbase,
                                                 const int* __restrict__ blkbase,
                                                 int* __restrict__ ebuf) {
  __shared__ int cur[NB];
  int i = blockIdx.x;
  int t = threadIdx.x;
  for (int b = t; b < NB; b += 256) cur[b] = bbase[b] + blkbase[i * NB + b];
  __syncthreads();
  int base = i * CHUNK;
  for (int e = base + t; e < base + CHUNK; e += 256) {
    int s = ei[e];
    int d = ei[NE + e];
    int b = d >> 7;
    int pos = atomicAdd(&cur[b], 1);
    ebuf[pos] = s | ((d & 127) << 17);
  }
}

// ============================================================
// Per-bucket CSR: 128-bin LDS count -> scan -> rowptr/dinv -> csrc fill.
// All LDS atomics; writes are within-bucket windows.
// ============================================================
__global__ __launch_bounds__(256) void k_bucket(const int* __restrict__ bbase,
                                                const int* __restrict__ ebuf,
                                                int* __restrict__ rowptr,
                                                float* __restrict__ dinv,
                                                int* __restrict__ csrc) {
  __shared__ int degL[128];
  __shared__ int sc[128];
  __shared__ int curL[128];
  int b = blockIdx.x;
  int t = threadIdx.x;
  int e0 = bbase[b], e1 = bbase[b + 1];
  if (t < 128) degL[t] = 0;
  __syncthreads();
  for (int e = e0 + t; e < e1; e += 256)
    atomicAdd(&degL[ebuf[e] >> 17], 1);
  __syncthreads();
  if (t < 128) sc[t] = degL[t];
  __syncthreads();
  for (int off = 1; off < 128; off <<= 1) {
    int xx = 0;
    if (t < 128 && t >= off) xx = sc[t - off];
    __syncthreads();
    if (t < 128) sc[t] += xx;
    __syncthreads();
  }
  if (t < 128) {
    int node = b * 128 + t;
    if (node < NN) {
      int d = degL[t];
      int exc = sc[t] - d;
      rowptr[node] = e0 + exc;
      dinv[node] = rsqrtf((float)(d + 1));   // +1 self-loop
      curL[t] = exc;
    }
  }
  if (b == NB - 1 && t == 0) rowptr[NN] = NE;
  __syncthreads();
  for (int e = e0 + t; e < e1; e += 256) {
    int p = ebuf[e];
    int pos = atomicAdd(&curL[p >> 17], 1);
    csrc[e0 + pos] = p & 0x1FFFF;
  }
}

// ============================================================
// MFMA f16 GEMM (register-only, no LDS), layers 2/3:
// Ht[r,:] = fp16( dinv[r] * ( BNReLU(A[r,:]) @ W ) ), K=128, BN_ cols.
// ============================================================
template <int BN_>
__global__ __launch_bounds__(256) void k_mgemm(const _Float16* __restrict__ A,
                                               const _Float16* __restrict__ Wt,
                                               const float* __restrict__ scale,
                                               const float* __restrict__ shift,
                                               const float* __restrict__ dinv,
                                               _Float16* __restrict__ C) {
  constexpr int NCT = BN_ / 32;
  int wid  = (blockIdx.x * 256 + threadIdx.x) >> 6;
  int lane = threadIdx.x & 63;
  if (wid >= NN / 32) return;
  const int m = lane & 31;
  const int q = lane >> 5;
  const int row0 = wid * 32;

  const _Float16* Arow = A + (size_t)(row0 + m) * 128 + q * 8;

  floatx16 acc[NCT] = {};

#pragma unroll
  for (int s = 0; s < 8; ++s) {
    half8 raw = *(const half8*)(Arow + 16 * s);
    int k0 = 16 * s + q * 8;
    half8 af;
#pragma unroll
    for (int j = 0; j < 8; ++j) {
      float a = fmaxf(fmaf((float)raw[j], scale[k0 + j], shift[k0 + j]), 0.f);
      af[j] = (_Float16)a;
    }
#pragma unroll
    for (int ct = 0; ct < NCT; ++ct) {
      half8 bf = *(const half8*)(Wt + (size_t)(ct * 32 + m) * 128 + q * 8 + 16 * s);
      acc[ct] = __builtin_amdgcn_mfma_f32_32x32x16_f16(af, bf, acc[ct], 0, 0, 0);
    }
  }

#pragma unroll
  for (int ct = 0; ct < NCT; ++ct)
#pragma unroll
    for (int r = 0; r < 16; ++r) {
      int row = (r & 3) + 8 * (r >> 2) + 4 * q;
      float dv = dinv[row0 + row];
      C[(size_t)(row0 + row) * BN_ + ct * 32 + m] = (_Float16)(acc[ct][r] * dv);
    }
}

// ============================================================
// Pull aggregation, D=128 fp16 -> fp16 (fp32 accumulate)
// SRCSCALE: multiply each gathered row by dinv[src] inline (layer 1,
// where Hf is stored unscaled).
// ============================================================
template <bool SRCSCALE>
__global__ __launch_bounds__(256) void k_agg128(const __half* __restrict__ H,
                                                const float* __restrict__ dinv,
                                                const int* __restrict__ rowptr,
                                                const int* __restrict__ srcs,
                                                __half2* __restrict__ out) {
  int wid  = (blockIdx.x * 256 + threadIdx.x) >> 6;
  int lane = threadIdx.x & 63;
  if (wid >= NN) return;
  const __half2* Hp = (const __half2*)H;
  float di = dinv[wid];
  float2 self = __half22float2(Hp[(size_t)wid * 64 + lane]);
  float2 acc;
  if (SRCSCALE) { acc.x = self.x * di; acc.y = self.y * di; }
  else          { acc = self; }
  int beg = rowptr[wid], end = rowptr[wid + 1];
  int e = beg;
  int end8 = beg + ((end - beg) & ~7);
  for (; e < end8; e += 8) {
    int s0 = srcs[e+0], s1 = srcs[e+1], s2 = srcs[e+2], s3 = srcs[e+3];
    int s4 = srcs[e+4], s5 = srcs[e+5], s6 = srcs[e+6], s7 = srcs[e+7];
    __half2 v0 = Hp[(size_t)s0 * 64 + lane];
    __half2 v1 = Hp[(size_t)s1 * 64 + lane];
    __half2 v2 = Hp[(size_t)s2 * 64 + lane];
    __half2 v3 = Hp[(size_t)s3 * 64 + lane];
    __half2 v4 = Hp[(size_t)s4 * 64 + lane];
    __half2 v5 = Hp[(size_t)s5 * 64 + lane];
    __half2 v6 = Hp[(size_t)s6 * 64 + lane];
    __half2 v7 = Hp[(size_t)s7 * 64 + lane];
    float2 f0 = __half22float2(v0), f1 = __half22float2(v1);
    float2 f2 = __half22float2(v2), f3 = __half22float2(v3);
    float2 f4 = __half22float2(v4), f5 = __half22float2(v5);
    float2 f6 = __half22float2(v6), f7 = __half22float2(v7);
    if (SRCSCALE) {
      float d0 = dinv[s0], d1 = dinv[s1], d2 = dinv[s2], d3 = dinv[s3];
      float d4 = dinv[s4], d5 = dinv[s5], d6 = dinv[s6], d7 = dinv[s7];
      acc.x = fmaf(f0.x, d0, acc.x); acc.y = fmaf(f0.y, d0, acc.y);
      acc.x = fmaf(f1.x, d1, acc.x); acc.y = fmaf(f1.y, d1, acc.y);
      acc.x = fmaf(f2.x, d2, acc.x); acc.y = fmaf(f2.y, d2, acc.y);
      acc.x = fmaf(f3.x, d3, acc.x); acc.y = fmaf(f3.y, d3, acc.y);
      acc.x = fmaf(f4.x, d4, acc.x); acc.y = fmaf(f4.y, d4, acc.y);
      acc.x = fmaf(f5.x, d5, acc.x); acc.y = fmaf(f5.y, d5, acc.y);
      acc.x = fmaf(f6.x, d6, acc.x); acc.y = fmaf(f6.y, d6, acc.y);
      acc.x = fmaf(f7.x, d7, acc.x); acc.y = fmaf(f7.y, d7, acc.y);
    } else {
      acc.x += (f0.x + f1.x) + (f2.x + f3.x) + (f4.x + f5.x) + (f6.x + f7.x);
      acc.y += (f0.y + f1.y) + (f2.y + f3.y) + (f4.y + f5.y) + (f6.y + f7.y);
    }
  }
  for (; e < end; ++e) {
    int s = srcs[e];
    float2 f = __half22float2(Hp[(size_t)s * 64 + lane]);
    if (SRCSCALE) {
      float dd = dinv[s];
      acc.x = fmaf(f.x, dd, acc.x); acc.y = fmaf(f.y, dd, acc.y);
    } else {
      acc.x += f.x; acc.y += f.y;
    }
  }
  out[(size_t)wid * 64 + lane] = __floats2half2_rn(acc.x * di, acc.y * di);
}

// ============================================================
// Final layer: aggregation (D=64, fp16) + bias + softmax
// ============================================================
__global__ __launch_bounds__(256) void k_agg64_softmax(const __half* __restrict__ H,
                                                       const float* __restrict__ dinv,
                                                       const int* __restrict__ rowptr,
                                                       const int* __restrict__ srcs,
                                                       const float* __restrict__ b3,
                                                       float* __restrict__ out) {
  int wid  = (blockIdx.x * 256 + threadIdx.x) >> 6;
  int lane = threadIdx.x & 63;
  if (wid >= NN) return;
  float acc = __half2float(H[(size_t)wid * 64 + lane]);   // self term
  int beg = rowptr[wid], end = rowptr[wid + 1];
  int e = beg;
  int end8 = beg + ((end - beg) & ~7);
  for (; e < end8; e += 8) {
    float v0 = __half2float(H[(size_t)srcs[e+0] * 64 + lane]);
    float v1 = __half2float(H[(size_t)srcs[e+1] * 64 + lane]);
    float v2 = __half2float(H[(size_t)srcs[e+2] * 64 + lane]);
    float v3 = __half2float(H[(size_t)srcs[e+3] * 64 + lane]);
    float v4 = __half2float(H[(size_t)srcs[e+4] * 64 + lane]);
    float v5 = __half2float(H[(size_t)srcs[e+5] * 64 + lane]);
    float v6 = __half2float(H[(size_t)srcs[e+6] * 64 + lane]);
    float v7 = __half2float(H[(size_t)srcs[e+7] * 64 + lane]);
    acc += (v0 + v1) + (v2 + v3) + (v4 + v5) + (v6 + v7);
  }
  for (; e < end; ++e)
    acc += __half2float(H[(size_t)srcs[e] * 64 + lane]);
  acc = acc * dinv[wid] + b3[lane];

  float m = acc;
#pragma unroll
  for (int off = 32; off > 0; off >>= 1) m = fmaxf(m, __shfl_xor(m, off));
  float ev = __expf(acc - m);
  float s = ev;
#pragma unroll
  for (int off = 32; off > 0; off >>= 1) s += __shfl_xor(s, off);
  out[(size_t)wid * 64 + lane] = ev / s;
}

// ============================================================
// BatchNorm column stats over fp16 h (fp32 accumulate)
// ============================================================
__global__ __launch_bounds__(256) void k_stats(const __half2* __restrict__ H2,
                                               float* __restrict__ S1,
                                               float* __restrict__ S2) {
  int t = threadIdx.x;
  int p = t & 63;
  int r = t >> 6;
  float2 s1 = {0.f, 0.f}, s2 = {0.f, 0.f};
  for (int row = blockIdx.x * 4 + r; row < NN; row += gridDim.x * 4) {
    float2 v = __half22float2(H2[(size_t)row * 64 + p]);
    s1.x += v.x; s1.y += v.y;
    s2.x += v.x * v.x; s2.y += v.y * v.y;
  }
  __shared__ float2 l1[256], l2[256];
  l1[t] = s1; l2[t] = s2;
  __syncthreads();
  if (t < 128) {
    l1[t].x += l1[t+128].x; l1[t].y += l1[t+128].y;
    l2[t].x += l2[t+128].x; l2[t].y += l2[t+128].y;
  }
  __syncthreads();
  if (t < 64) {
    float2 a1 = l1[t], b1 = l1[t+64];
    float2 a2 = l2[t], b2 = l2[t+64];
    atomicAdd(&S1[2*p+0], a1.x + b1.x);
    atomicAdd(&S1[2*p+1], a1.y + b1.y);
    atomicAdd(&S2[2*p+0], a2.x + b2.x);
    atomicAdd(&S2[2*p+1], a2.y + b2.y);
  }
}

__global__ void k_finalize(const float* __restrict__ S1, const float* __restrict__ S2,
                           const float* __restrict__ g,  const float* __restrict__ be,
                           float* __restrict__ scale,    float* __restrict__ shift) {
  int t = threadIdx.x;  // 128 threads
  float mean = S1[t] * (1.0f / NN);
  float var  = S2[t] * (1.0f / NN) - mean * mean;
  float is   = rsqrtf(var + BN_EPS);
  float sc   = g[t] * is;
  scale[t] = sc;
  shift[t] = be[t] - mean * sc;
}

// ============================================================
// host launch
// ============================================================
extern "C" void kernel_launch(void* const* d_in, const int* in_sizes, int n_in,
                              void* d_out, int out_size, void* d_ws, size_t ws_size,
                              hipStream_t stream) {
  (void)in_sizes; (void)n_in; (void)out_size; (void)ws_size;
  const float* x   = (const float*)d_in[0];
  const int*   ei  = (const int*)d_in[1];
  const float* W1  = (const float*)d_in[2];
  // d_in[3] = b1: cancels in BatchNorm (constant column shift), skipped
  const float* W2  = (const float*)d_in[4];
  // d_in[5] = b2: same
  const float* W3  = (const float*)d_in[6];
  const float* b3  = (const float*)d_in[7];
  const float* g1  = (const float*)d_in[8];
  const float* be1 = (const float*)d_in[9];
  const float* g2  = (const float*)d_in[10];
  const float* be2 = (const float*)d_in[11];
  float* out = (float*)d_out;

  char* ws = (char*)d_ws;
  size_t off = 0;
  auto take = [&](size_t bytes) -> char* {
    char* p = ws + off;
    off = (off + bytes + 255) & ~(size_t)255;
    return p;
  };
  float* S1a    = (float*)take(128 * 4);
  float* S2a    = (float*)take(128 * 4);
  float* S1b    = (float*)take(128 * 4);
  float* S2b    = (float*)take(128 * 4);
  size_t zero_bytes = off;                  // stats accumulators zeroed each call
  float* scale1 = (float*)take(128 * 4);
  float* shift1 = (float*)take(128 * 4);
  float* scale2 = (float*)take(128 * 4);
  float* shift2 = (float*)take(128 * 4);
  float* dinv   = (float*)take((size_t)NN * 4);
  int*   rowptr = (int*)  take((size_t)(NN + 1) * 4);
  int*   bbase  = (int*)  take((size_t)(NB + 1) * 4);
  int*   total  = (int*)  take((size_t)NB * 4);
  int*   blkhist= (int*)  take((size_t)HB * NB * 4);
  int*   blkbase= (int*)  take((size_t)HB * NB * 4);
  int*   ebuf   = (int*)  take((size_t)NE * 4);
  int*   csrc   = (int*)  take((size_t)NE * 4);
  _Float16* Wt1 = (_Float16*)take((size_t)128 * 128 * 2);
  _Float16* Wt2 = (_Float16*)take((size_t)128 * 128 * 2);
  _Float16* Wt3 = (_Float16*)take((size_t)64 * 128 * 2);
  _Float16* Hf  = (_Float16*)take((size_t)NN * 128 * 2);  // fp16 gather table
  _Float16* hB  = (_Float16*)take((size_t)NN * 128 * 2);  // fp16 agg output

  (void)hipMemsetAsync(d_ws, 0, zero_bytes, stream);

  const int mgB  = MG_B;                    // 782
  const int aggB = (NN + 3) / 4;            // 25000
  const int scanAB = (NB + 3) / 4;          // 196 (4 waves/block)

  k_wprep_all<<<160, 256, 0, stream>>>(W1, W2, W3, Wt1, Wt2, Wt3);

  // F1: layer-1 GEMM (unscaled) overlapped with bucket histograms (no atomics)
  k_f1<<<MG_B + HB, 256, 0, stream>>>(ei + NE, blkhist, x, Wt1, Hf);

  // deterministic bucket-sort CSR build
  k_scan_bkt_a<<<scanAB, 256, 0, stream>>>(blkhist, blkbase, total);
  k_scan_bkt_b<<<1, 1024, 0, stream>>>(total, bbase);
  k_scatter<<<HB, 256, 0, stream>>>(ei, bbase, blkbase, ebuf);
  k_bucket<<<NB, 256, 0, stream>>>(bbase, ebuf, rowptr, dinv, csrc);

  // layer 1 tail: aggregation applies dinv[src] inline (Hf unscaled)
  k_agg128<true><<<aggB, 256, 0, stream>>>((const __half*)Hf, dinv, rowptr, csrc, (__half2*)hB);
  k_stats<<<1024, 256, 0, stream>>>((const __half2*)hB, S1a, S2a);
  k_finalize<<<1, 128, 0, stream>>>(S1a, S2a, g1, be1, scale1, shift1);

  // layer 2 (BN+ReLU fused into GEMM A-load; dinv baked into epilogue)
  k_mgemm<128><<<mgB, 256, 0, stream>>>(hB, Wt2, scale1, shift1, dinv, Hf);
  k_agg128<false><<<aggB, 256, 0, stream>>>((const __half*)Hf, dinv, rowptr, csrc, (__half2*)hB);
  k_stats<<<1024, 256, 0, stream>>>((const __half2*)hB, S1b, S2b);
  k_finalize<<<1, 128, 0, stream>>>(S1b, S2b, g2, be2, scale2, shift2);

  // layer 3 (BN+ReLU fused) -> N x 64 fp16, then aggregation + bias + softmax
  k_mgemm<64><<<mgB, 256, 0, stream>>>(hB, Wt3, scale2, shift2, dinv, Hf);
  k_agg64_softmax<<<aggB, 256, 0, stream>>>((const __half*)Hf, dinv, rowptr, csrc, b3, out);
}

// Round 2
// 685.263 us; speedup vs baseline: 1.2265x; 1.0688x over previous
//
#include <hip/hip_runtime.h>
#include <hip/hip_fp16.h>

// ---------------- problem constants ----------------
constexpr int   NN   = 100000;      // nodes
constexpr int   NE   = 3200000;     // edges
constexpr float BN_EPS = 1e-5f;

constexpr int MG_B  = (NN / 32 + 3) / 4;   // 782 mgemm blocks (3125 waves)
constexpr int NB    = (NN + 127) / 128;    // 782 buckets (128 nodes each)
constexpr int HB    = 256;                 // histogram / scatter blocks
constexpr int CHUNK = NE / HB;             // 12500 edges per chunk (exact)
constexpr int BKT_CAP = 5120;              // LDS sort capacity (avg 4096, sd~64)

typedef _Float16 half8 __attribute__((ext_vector_type(8)));
typedef float    floatx16 __attribute__((ext_vector_type(16)));
typedef float    floatx8  __attribute__((ext_vector_type(8)));

// ============================================================
// Weight prep (all 3): Wt[n][k] = fp16(W[k][n])
// ============================================================
__global__ __launch_bounds__(256) void k_wprep_all(const float* __restrict__ W1,
                                                   const float* __restrict__ W2,
                                                   const float* __restrict__ W3,
                                                   _Float16* __restrict__ Wt1,
                                                   _Float16* __restrict__ Wt2,
                                                   _Float16* __restrict__ Wt3) {
  int idx = blockIdx.x * 256 + threadIdx.x;
  if (idx < 16384) {
    int k = idx >> 7, n = idx & 127;
    Wt1[n * 128 + k] = (_Float16)W1[idx];
  } else if (idx < 32768) {
    int j = idx - 16384, k = j >> 7, n = j & 127;
    Wt2[n * 128 + k] = (_Float16)W2[j];
  } else if (idx < 40960) {
    int j = idx - 32768, k = j >> 6, n = j & 63;
    Wt3[n * 128 + k] = (_Float16)W3[j];
  }
}

// ============================================================
// F1: fused  [blocks 0..MG_B)       : layer-1 MFMA GEMM (UNSCALED fp16 out)
//            [MG_B..MG_B+HB)        : per-chunk LDS histogram over 782 buckets
// No global atomics anywhere: each hist block writes its own blkhist row.
// ============================================================
__global__ __launch_bounds__(256) void k_f1(const int* __restrict__ dst,
                                            int* __restrict__ blkhist,
                                            const float* __restrict__ x,
                                            const _Float16* __restrict__ Wt1,
                                            _Float16* __restrict__ C) {
  __shared__ int h[NB];
  if (blockIdx.x < MG_B) {
    // ---- mgemm<128, no BN, fp32 A, no dinv> ----
    int wid  = (blockIdx.x * 256 + threadIdx.x) >> 6;
    int lane = threadIdx.x & 63;
    if (wid >= NN / 32) return;
    const int m = lane & 31;
    const int q = lane >> 5;
    const int row0 = wid * 32;
    const float* Arow = x + (size_t)(row0 + m) * 128 + q * 8;

    floatx16 acc[4] = {};
#pragma unroll
    for (int s = 0; s < 8; ++s) {
      float4 a0 = *(const float4*)(Arow + 16 * s);
      float4 a1 = *(const float4*)(Arow + 16 * s + 4);
      half8 af;
      af[0] = (_Float16)a0.x; af[1] = (_Float16)a0.y;
      af[2] = (_Float16)a0.z; af[3] = (_Float16)a0.w;
      af[4] = (_Float16)a1.x; af[5] = (_Float16)a1.y;
      af[6] = (_Float16)a1.z; af[7] = (_Float16)a1.w;
#pragma unroll
      for (int ct = 0; ct < 4; ++ct) {
        half8 bf = *(const half8*)(Wt1 + (size_t)(ct * 32 + m) * 128 + q * 8 + 16 * s);
        acc[ct] = __builtin_amdgcn_mfma_f32_32x32x16_f16(af, bf, acc[ct], 0, 0, 0);
      }
    }
#pragma unroll
    for (int ct = 0; ct < 4; ++ct)
#pragma unroll
      for (int r = 0; r < 16; ++r) {
        int row = (r & 3) + 8 * (r >> 2) + 4 * q;   // C/D map [m74/m101]
        C[(size_t)(row0 + row) * 128 + ct * 32 + m] = (_Float16)acc[ct][r];
      }
  } else {
    int j = blockIdx.x - MG_B;        // chunk id 0..HB-1
    int t = threadIdx.x;
    for (int b = t; b < NB; b += 256) h[b] = 0;
    __syncthreads();
    int base = j * CHUNK;
    for (int e = base + t; e < base + CHUNK; e += 256)
      atomicAdd(&h[dst[e] >> 7], 1);                 // LDS atomic (fast)
    __syncthreads();
    for (int b = t; b < NB; b += 256) blkhist[j * NB + b] = h[b];
  }
}

// ============================================================
// Per-bucket exclusive scan over the 256 block counts.
// One wave per bucket; lane l handles blocks 4l..4l+3.
// ============================================================
__global__ __launch_bounds__(256) void k_scan_bkt_a(const int* __restrict__ blkhist,
                                                    int* __restrict__ blkbase,
                                                    int* __restrict__ total) {
  int wid  = (blockIdx.x * 256 + threadIdx.x) >> 6;
  int lane = threadIdx.x & 63;
  if (wid >= NB) return;
  int i0 = lane * 4;
  int v0 = blkhist[(i0 + 0) * NB + wid];
  int v1 = blkhist[(i0 + 1) * NB + wid];
  int v2 = blkhist[(i0 + 2) * NB + wid];
  int v3 = blkhist[(i0 + 3) * NB + wid];
  int lt = v0 + v1 + v2 + v3;
  int inc = lt;
#pragma unroll
  for (int off = 1; off < 64; off <<= 1) {
    int xx = __shfl_up(inc, off);
    if (lane >= off) inc += xx;
  }
  int exc = inc - lt;
  blkbase[(i0 + 0) * NB + wid] = exc;
  blkbase[(i0 + 1) * NB + wid] = exc + v0;
  blkbase[(i0 + 2) * NB + wid] = exc + v0 + v1;
  blkbase[(i0 + 3) * NB + wid] = exc + v0 + v1 + v2;
  if (lane == 63) total[wid] = inc;
}

// exclusive scan of 782 bucket totals -> bucket bases (+E sentinel)
__global__ __launch_bounds__(1024) void k_scan_bkt_b(const int* __restrict__ total,
                                                     int* __restrict__ bbase) {
  __shared__ int s[1024];
  int t = threadIdx.x;
  int v = (t < NB) ? total[t] : 0;
  s[t] = v;
  __syncthreads();
  for (int off = 1; off < 1024; off <<= 1) {
    int xx = (t >= off) ? s[t - off] : 0;
    __syncthreads();
    s[t] += xx;
    __syncthreads();
  }
  if (t < NB) bbase[t] = s[t] - v;
  if (t == NB - 1) bbase[NB] = s[t];   // == NE
}

// ============================================================
// Scatter edges into bucket order. Deterministic global positions:
// cursor[b] = bbase[b] + blkbase[chunk][b]; local order via LDS atomics.
// Packed edge: src (17b) | dlow (7b) << 17
// ============================================================
__global__ __launch_bounds__(256) void k_scatter(const int* __restrict__ ei,
                                                 const int* __restrict__ bbase,
                                                 const int* __restrict__ blkbase,
                                                 int* __restrict__ ebuf) {
  __shared__ int cur[NB];
  int i = blockIdx.x;
  int t = threadIdx.x;
  for (int b = t; b < NB; b += 256) cur[b] = bbase[b] + blkbase[i * NB + b];
  __syncthreads();
  int base = i * CHUNK;
  for (int e = base + t; e < base + CHUNK; e += 256) {
    int s = ei[e];
    int d = ei[NE + e];
    int b = d >> 7;
    int pos = atomicAdd(&cur[b], 1);
    ebuf[pos] = s | ((d & 127) << 17);
  }
}

// ============================================================
// Per-bucket CSR: 128-bin LDS count -> scan -> rowptr/dinv -> LDS sort
// -> coalesced csrc write. (fallback to direct scatter if oversized)
// ============================================================
__global__ __launch_bounds__(256) void k_bucket(const int* __restrict__ bbase,
                                                const int* __restrict__ ebuf,
                                                int* __restrict__ rowptr,
                                                float* __restrict__ dinv,
                                                int* __restrict__ csrc) {
  __shared__ int degL[128];
  __shared__ int sc[128];
  __shared__ int curL[128];
  __shared__ int sorted[BKT_CAP];
  int b = blockIdx.x;
  int t = threadIdx.x;
  int e0 = bbase[b], e1 = bbase[b + 1];
  int cnt = e1 - e0;
  if (t < 128) degL[t] = 0;
  __syncthreads();
  for (int e = e0 + t; e < e1; e += 256)
    atomicAdd(&degL[ebuf[e] >> 17], 1);
  __syncthreads();
  if (t < 128) sc[t] = degL[t];
  __syncthreads();
  for (int off = 1; off < 128; off <<= 1) {
    int xx = 0;
    if (t < 128 && t >= off) xx = sc[t - off];
    __syncthreads();
    if (t < 128) sc[t] += xx;
    __syncthreads();
  }
  if (t < 128) {
    int node = b * 128 + t;
    if (node < NN) {
      int d = degL[t];
      int exc = sc[t] - d;
      rowptr[node] = e0 + exc;
      dinv[node] = rsqrtf((float)(d + 1));   // +1 self-loop
      curL[t] = exc;
    }
  }
  if (b == NB - 1 && t == 0) rowptr[NN] = NE;
  __syncthreads();
  if (cnt <= BKT_CAP) {
    for (int e = e0 + t; e < e1; e += 256) {
      int p = ebuf[e];
      int pos = atomicAdd(&curL[p >> 17], 1);
      sorted[pos] = p & 0x1FFFF;
    }
    __syncthreads();
    for (int i = t; i < cnt; i += 256) csrc[e0 + i] = sorted[i];
  } else {
    for (int e = e0 + t; e < e1; e += 256) {
      int p = ebuf[e];
      int pos = atomicAdd(&curL[p >> 17], 1);
      csrc[e0 + pos] = p & 0x1FFFF;
    }
  }
}

// ============================================================
// MFMA f16 GEMM (register-only, no LDS), layers 2/3:
// Ht[r,:] = fp16( dinv[r] * ( BNReLU(A[r,:]) @ W ) ), K=128, BN_ cols.
// ============================================================
template <int BN_>
__global__ __launch_bounds__(256) void k_mgemm(const _Float16* __restrict__ A,
                                               const _Float16* __restrict__ Wt,
                                               const float* __restrict__ scale,
                                               const float* __restrict__ shift,
                                               const float* __restrict__ dinv,
                                               _Float16* __restrict__ C) {
  constexpr int NCT = BN_ / 32;
  int wid  = (blockIdx.x * 256 + threadIdx.x) >> 6;
  int lane = threadIdx.x & 63;
  if (wid >= NN / 32) return;
  const int m = lane & 31;
  const int q = lane >> 5;
  const int row0 = wid * 32;

  const _Float16* Arow = A + (size_t)(row0 + m) * 128 + q * 8;

  floatx16 acc[NCT] = {};

#pragma unroll
  for (int s = 0; s < 8; ++s) {
    half8 raw = *(const half8*)(Arow + 16 * s);
    int k0 = 16 * s + q * 8;
    half8 af;
#pragma unroll
    for (int j = 0; j < 8; ++j) {
      float a = fmaxf(fmaf((float)raw[j], scale[k0 + j], shift[k0 + j]), 0.f);
      af[j] = (_Float16)a;
    }
#pragma unroll
    for (int ct = 0; ct < NCT; ++ct) {
      half8 bf = *(const half8*)(Wt + (size_t)(ct * 32 + m) * 128 + q * 8 + 16 * s);
      acc[ct] = __builtin_amdgcn_mfma_f32_32x32x16_f16(af, bf, acc[ct], 0, 0, 0);
    }
  }

#pragma unroll
  for (int ct = 0; ct < NCT; ++ct)
#pragma unroll
    for (int r = 0; r < 16; ++r) {
      int row = (r & 3) + 8 * (r >> 2) + 4 * q;
      float dv = dinv[row0 + row];
      C[(size_t)(row0 + row) * BN_ + ct * 32 + m] = (_Float16)(acc[ct][r] * dv);
    }
}

// ============================================================
// Pull aggregation, D=128 fp16 -> fp16 (fp32 accumulate)
// 16 lanes per gathered row (dwordx4/lane) -> 4 edges per wave-load.
// Edge group g = lane>>4 handles edges beg+g, beg+g+4, ...
// Cross-group merge via shfl_xor(16,32) at the end.
// SRCSCALE: multiply each gathered row by dinv[src] inline (layer 1).
// ============================================================
template <bool SRCSCALE>
__global__ __launch_bounds__(256) void k_agg128(const __half* __restrict__ H,
                                                const float* __restrict__ dinv,
                                                const int* __restrict__ rowptr,
                                                const int* __restrict__ srcs,
                                                __half2* __restrict__ out) {
  int wid  = (blockIdx.x * 256 + threadIdx.x) >> 6;
  int lane = threadIdx.x & 63;
  if (wid >= NN) return;
  const int g  = lane >> 4;     // edge group 0..3
  const int sl = lane & 15;     // column slice: halves sl*8 .. sl*8+7
  const _Float16* Hb = (const _Float16*)H + (size_t)sl * 8;
  float di = dinv[wid];
  floatx8 acc = {};
  if (g == 0) {                 // self term
    half8 h = *(const half8*)(Hb + (size_t)wid * 128);
    float ds = SRCSCALE ? di : 1.f;
#pragma unroll
    for (int j = 0; j < 8; ++j) acc[j] = (float)h[j] * ds;
  }
  int beg = rowptr[wid], end = rowptr[wid + 1];
  int e = beg + g;
  for (; e + 4 < end; e += 8) {          // 2 edges per group per iter
    int s0 = srcs[e];
    int s1 = srcs[e + 4];
    half8 h0 = *(const half8*)(Hb + (size_t)s0 * 128);
    half8 h1 = *(const half8*)(Hb + (size_t)s1 * 128);
    if (SRCSCALE) {
      float d0 = dinv[s0], d1 = dinv[s1];
#pragma unroll
      for (int j = 0; j < 8; ++j) {
        acc[j] = fmaf((float)h0[j], d0, acc[j]);
        acc[j] = fmaf((float)h1[j], d1, acc[j]);
      }
    } else {
#pragma unroll
      for (int j = 0; j < 8; ++j)
        acc[j] += (float)h0[j] + (float)h1[j];
    }
  }
  if (e < end) {                          // per-group tail (<=1 edge)
    int s0 = srcs[e];
    half8 h0 = *(const half8*)(Hb + (size_t)s0 * 128);
    float d0 = SRCSCALE ? dinv[s0] : 1.f;
#pragma unroll
    for (int j = 0; j < 8; ++j) acc[j] = fmaf((float)h0[j], d0, acc[j]);
  }
#pragma unroll
  for (int j = 0; j < 8; ++j) {
    acc[j] += __shfl_xor(acc[j], 16);
    acc[j] += __shfl_xor(acc[j], 32);
  }
  if (g == 0) {
    __half2 o[4];
#pragma unroll
    for (int j = 0; j < 4; ++j)
      o[j] = __floats2half2_rn(acc[2 * j] * di, acc[2 * j + 1] * di);
    *(int4*)(out + (size_t)wid * 64 + sl * 4) = *(const int4*)o;
  }
}

// ============================================================
// Final layer: aggregation (D=64, fp16, 8 lanes/row -> 8 edges per
// wave-load) + bias + softmax (column reduce over lane bits 0..2)
// ============================================================
__global__ __launch_bounds__(256) void k_agg64_softmax(const __half* __restrict__ H,
                                                       const float* __restrict__ dinv,
                                                       const int* __restrict__ rowptr,
                                                       const int* __restrict__ srcs,
                                                       const float* __restrict__ b3,
                                                       float* __restrict__ out) {
  int wid  = (blockIdx.x * 256 + threadIdx.x) >> 6;
  int lane = threadIdx.x & 63;
  if (wid >= NN) return;
  const int g  = lane >> 3;     // edge group 0..7
  const int sl = lane & 7;      // column slice: cols sl*8 .. sl*8+7
  const _Float16* Hb = (const _Float16*)H + (size_t)sl * 8;
  floatx8 acc = {};
  if (g == 0) {                 // self term
    half8 h = *(const half8*)(Hb + (size_t)wid * 64);
#pragma unroll
    for (int j = 0; j < 8; ++j) acc[j] = (float)h[j];
  }
  int beg = rowptr[wid], end = rowptr[wid + 1];
  int e = beg + g;
  for (; e + 8 < end; e += 16) {         // 2 edges per group per iter
    int s0 = srcs[e];
    int s1 = srcs[e + 8];
    half8 h0 = *(const half8*)(Hb + (size_t)s0 * 64);
    half8 h1 = *(const half8*)(Hb + (size_t)s1 * 64);
#pragma unroll
    for (int j = 0; j < 8; ++j)
      acc[j] += (float)h0[j] + (float)h1[j];
  }
  if (e < end) {
    int s0 = srcs[e];
    half8 h0 = *(const half8*)(Hb + (size_t)s0 * 64);
#pragma unroll
    for (int j = 0; j < 8; ++j) acc[j] += (float)h0[j];
  }
#pragma unroll
  for (int j = 0; j < 8; ++j) {
    acc[j] += __shfl_xor(acc[j], 8);
    acc[j] += __shfl_xor(acc[j], 16);
    acc[j] += __shfl_xor(acc[j], 32);
  }
  float di = dinv[wid];
  float4 bA = *(const float4*)(b3 + sl * 8);
  float4 bB = *(const float4*)(b3 + sl * 8 + 4);
  float v[8];
  v[0] = acc[0] * di + bA.x; v[1] = acc[1] * di + bA.y;
  v[2] = acc[2] * di + bA.z; v[3] = acc[3] * di + bA.w;
  v[4] = acc[4] * di + bB.x; v[5] = acc[5] * di + bB.y;
  v[6] = acc[6] * di + bB.z; v[7] = acc[7] * di + bB.w;
  float m = v[0];
#pragma unroll
  for (int j = 1; j < 8; ++j) m = fmaxf(m, v[j]);
  m = fmaxf(m, __shfl_xor(m, 1));
  m = fmaxf(m, __shfl_xor(m, 2));
  m = fmaxf(m, __shfl_xor(m, 4));
  float s = 0.f;
#pragma unroll
  for (int j = 0; j < 8; ++j) { v[j] = __expf(v[j] - m); s += v[j]; }
  s += __shfl_xor(s, 1);
  s += __shfl_xor(s, 2);
  s += __shfl_xor(s, 4);
  float inv = 1.0f / s;
  if (g == 0) {
    float4 oA = {v[0] * inv, v[1] * inv, v[2] * inv, v[3] * inv};
    float4 oB = {v[4] * inv, v[5] * inv, v[6] * inv, v[7] * inv};
    *(float4*)(out + (size_t)wid * 64 + sl * 8)     = oA;
    *(float4*)(out + (size_t)wid * 64 + sl * 8 + 4) = oB;
  }
}

// ============================================================
// BatchNorm column stats over fp16 h (fp32 accumulate)
// ============================================================
__global__ __launch_bounds__(256) void k_stats(const __half2* __restrict__ H2,
                                               float* __restrict__ S1,
                                               float* __restrict__ S2) {
  int t = threadIdx.x;
  int p = t & 63;
  int r = t >> 6;
  float2 s1 = {0.f, 0.f}, s2 = {0.f, 0.f};
  for (int row = blockIdx.x * 4 + r; row < NN; row += gridDim.x * 4) {
    float2 v = __half22float2(H2[(size_t)row * 64 + p]);
    s1.x += v.x; s1.y += v.y;
    s2.x += v.x * v.x; s2.y += v.y * v.y;
  }
  __shared__ float2 l1[256], l2[256];
  l1[t] = s1; l2[t] = s2;
  __syncthreads();
  if (t < 128) {
    l1[t].x += l1[t+128].x; l1[t].y += l1[t+128].y;
    l2[t].x += l2[t+128].x; l2[t].y += l2[t+128].y;
  }
  __syncthreads();
  if (t < 64) {
    float2 a1 = l1[t], b1 = l1[t+64];
    float2 a2 = l2[t], b2 = l2[t+64];
    atomicAdd(&S1[2*p+0], a1.x + b1.x);
    atomicAdd(&S1[2*p+1], a1.y + b1.y);
    atomicAdd(&S2[2*p+0], a2.x + b2.x);
    atomicAdd(&S2[2*p+1], a2.y + b2.y);
  }
}

__global__ void k_finalize(const float* __restrict__ S1, const float* __restrict__ S2,
                           const float* __restrict__ g,  const float* __restrict__ be,
                           float* __restrict__ scale,    float* __restrict__ shift) {
  int t = threadIdx.x;  // 128 threads
  float mean = S1[t] * (1.0f / NN);
  float var  = S2[t] * (1.0f / NN) - mean * mean;
  float is   = rsqrtf(var + BN_EPS);
  float sc   = g[t] * is;
  scale[t] = sc;
  shift[t] = be[t] - mean * sc;
}

// ============================================================
// host launch
// ============================================================
extern "C" void kernel_launch(void* const* d_in, const int* in_sizes, int n_in,
                              void* d_out, int out_size, void* d_ws, size_t ws_size,
                              hipStream_t stream) {
  (void)in_sizes; (void)n_in; (void)out_size; (void)ws_size;
  const float* x   = (const float*)d_in[0];
  const int*   ei  = (const int*)d_in[1];
  const float* W1  = (const float*)d_in[2];
  // d_in[3] = b1: cancels in BatchNorm (constant column shift), skipped
  const float* W2  = (const float*)d_in[4];
  // d_in[5] = b2: same
  const float* W3  = (const float*)d_in[6];
  const float* b3  = (const float*)d_in[7];
  const float* g1  = (const float*)d_in[8];
  const float* be1 = (const float*)d_in[9];
  const float* g2  = (const float*)d_in[10];
  const float* be2 = (const float*)d_in[11];
  float* out = (float*)d_out;

  char* ws = (char*)d_ws;
  size_t off = 0;
  auto take = [&](size_t bytes) -> char* {
    char* p = ws + off;
    off = (off + bytes + 255) & ~(size_t)255;
    return p;
  };
  float* S1a    = (float*)take(128 * 4);
  float* S2a    = (float*)take(128 * 4);
  float* S1b    = (float*)take(128 * 4);
  float* S2b    = (float*)take(128 * 4);
  size_t zero_bytes = off;                  // stats accumulators zeroed each call
  float* scale1 = (float*)take(128 * 4);
  float* shift1 = (float*)take(128 * 4);
  float* scale2 = (float*)take(128 * 4);
  float* shift2 = (float*)take(128 * 4);
  float* dinv   = (float*)take((size_t)NN * 4);
  int*   rowptr = (int*)  take((size_t)(NN + 1) * 4);
  int*   bbase  = (int*)  take((size_t)(NB + 1) * 4);
  int*   total  = (int*)  take((size_t)NB * 4);
  int*   blkhist= (int*)  take((size_t)HB * NB * 4);
  int*   blkbase= (int*)  take((size_t)HB * NB * 4);
  int*   ebuf   = (int*)  take((size_t)NE * 4);
  int*   csrc   = (int*)  take((size_t)NE * 4);
  _Float16* Wt1 = (_Float16*)take((size_t)128 * 128 * 2);
  _Float16* Wt2 = (_Float16*)take((size_t)128 * 128 * 2);
  _Float16* Wt3 = (_Float16*)take((size_t)64 * 128 * 2);
  _Float16* Hf  = (_Float16*)take((size_t)NN * 128 * 2);  // fp16 gather table
  _Float16* hB  = (_Float16*)take((size_t)NN * 128 * 2);  // fp16 agg output

  (void)hipMemsetAsync(d_ws, 0, zero_bytes, stream);

  const int mgB  = MG_B;                    // 782
  const int aggB = (NN + 3) / 4;            // 25000
  const int scanAB = (NB + 3) / 4;          // 196 (4 waves/block)

  k_wprep_all<<<160, 256, 0, stream>>>(W1, W2, W3, Wt1, Wt2, Wt3);

  // F1: layer-1 GEMM (unscaled) overlapped with bucket histograms (no atomics)
  k_f1<<<MG_B + HB, 256, 0, stream>>>(ei + NE, blkhist, x, Wt1, Hf);

  // deterministic bucket-sort CSR build
  k_scan_bkt_a<<<scanAB, 256, 0, stream>>>(blkhist, blkbase, total);
  k_scan_bkt_b<<<1, 1024, 0, stream>>>(total, bbase);
  k_scatter<<<HB, 256, 0, stream>>>(ei, bbase, blkbase, ebuf);
  k_bucket<<<NB, 256, 0, stream>>>(bbase, ebuf, rowptr, dinv, csrc);

  // layer 1 tail: aggregation applies dinv[src] inline (Hf unscaled)
  k_agg128<true><<<aggB, 256, 0, stream>>>((const __half*)Hf, dinv, rowptr, csrc, (__half2*)hB);
  k_stats<<<1024, 256, 0, stream>>>((const __half2*)hB, S1a, S2a);
  k_finalize<<<1, 128, 0, stream>>>(S1a, S2a, g1, be1, scale1, shift1);

  // layer 2 (BN+ReLU fused into GEMM A-load; dinv baked into epilogue)
  k_mgemm<128><<<mgB, 256, 0, stream>>>(hB, Wt2, scale1, shift1, dinv, Hf);
  k_agg128<false><<<aggB, 256, 0, stream>>>((const __half*)Hf, dinv, rowptr, csrc, (__half2*)hB);
  k_stats<<<1024, 256, 0, stream>>>((const __half2*)hB, S1b, S2b);
  k_finalize<<<1, 128, 0, stream>>>(S1b, S2b, g2, be2, scale2, shift2);

  // layer 3 (BN+ReLU fused) -> N x 64 fp16, then aggregation + bias + softmax
  k_mgemm<64><<<mgB, 256, 0, stream>>>(hB, Wt3, scale2, shift2, dinv, Hf);
  k_agg64_softmax<<<aggB, 256, 0, stream>>>((const __half*)Hf, dinv, rowptr, csrc, b3, out);
}